// Round 4
// baseline (166.230 us; speedup 1.0000x reference)
//
#include <hip/hip_runtime.h>

// B=2, Hi=Wi=64, Di=32, C=16, F=8, strides (2,2,2), k=3x3x3, Ho=Wo=128, Do=64.
constexpr int Bc  = 2;
constexpr int HiC = 64, WiC = 64, DiC = 32;
constexpr int Cc  = 16, Fc  = 8;
constexpr int HoC = 128, WoC = 128, DoC = 64;

// Named members only — pointer-out-param arrays get demoted to scratch (round 2:
// 822 MB WRITE_SIZE). Tap = one input row (16 ch); TapSet = the 3 kd-taps of a
// spatial position (kd=0,2 feed the even-dn row; kd=1 feeds the odd-dn row).
struct Tap    { float4 a, b, c, d; };
struct TapSet { Tap e0, e2, o1; };

__device__ __forceinline__ Tap ldtap(const float4* __restrict__ p) {
    Tap t; t.a = p[0]; t.b = p[1]; t.c = p[2]; t.d = p[3]; return t;
}

// w has a wave-uniform address -> s_load; v_fma with one SGPR operand.
__device__ __forceinline__ float dot16(const Tap& t, const float* __restrict__ w) {
    return t.a.x * w[0]  + t.a.y * w[1]  + t.a.z * w[2]  + t.a.w * w[3]
         + t.b.x * w[4]  + t.b.y * w[5]  + t.b.z * w[6]  + t.b.w * w[7]
         + t.c.x * w[8]  + t.c.y * w[9]  + t.c.z * w[10] + t.c.w * w[11]
         + t.d.x * w[12] + t.d.y * w[13] + t.d.z * w[14] + t.d.w * w[15];
}

// Wave = 2 same-parity columns; lane = (half, rr) owns depth pair (doE, doO).
// Valid spatial positions npos in {1,2,4} are wave-uniform; iterated as a
// uniform loop with 1-deep tap prefetch and 2-deep bpg prefetch.
__global__ __launch_bounds__(256, 3)
void sconv3dt_kernel(const float* __restrict__ images,
                     const int*   __restrict__ base_plane,
                     const float* __restrict__ kern,
                     float*       __restrict__ out,
                     const float* __restrict__ zpad) {
    const int t    = threadIdx.x;
    const int wv   = t >> 6;
    const int lane = t & 63;
    const int half = lane >> 5;
    const int rr   = lane & 31;
    const int b    = blockIdx.z;
    const int ho   = blockIdx.y;
    const int wo   = (blockIdx.x << 3) + (wv & 1) + ((wv >> 1) << 2) + (half << 1);

    const int bp_col = base_plane[(b * HoC + ho) * WoC + wo];
    const int q   = (bp_col + 1) & 1;
    const int doE = 2 * rr + q;          // (bp+do+1) even -> kd in {0,2}
    const int doO = 2 * rr + 1 - q;      // (bp+do+1) odd  -> kd = 1
    const int hEc = (bp_col + doE + 1) >> 1;   // di(kd0)=hEc-bpg; kd2:-1; kd1:-q

    const int  hoOdd = ho & 1;
    const int  woOdd = wo & 1;           // wave-uniform (columns share parity)
    const int  khA   = hoOdd ? 0 : 1;
    const int  kwA   = woOdd ? 0 : 1;
    const bool mhA   = !hoOdd || (ho + 1 < HoC);   // block-uniform edge mask
    const bool mwA   = !woOdd || (wo + 1 < WoC);   // per-lane at right edge only
    const int  npos  = (hoOdd ? 2 : 1) * (woOdd ? 2 : 1);   // wave-uniform

    // Position schedule p=0..npos-1: ph/pw pick kh in {khA,2}, kw in {kwA,2}.
    auto PH = [&](int p) { return woOdd ? (p >> 1) : p; };
    auto PW = [&](int p) { return woOdd ? (p & 1) : 0; };

    auto bpload = [&](int p) -> int {   // stage 1: issue the bpg read only
        const int kh = PH(p) ? 2 : khA;
        const int kw = PW(p) ? 2 : kwA;
        int hi = (ho + 1 - kh) >> 1; hi = hi < 0 ? 0 : (hi > HiC - 1 ? HiC - 1 : hi);
        int wi = (wo + 1 - kw) >> 1; wi = wi < 0 ? 0 : (wi > WiC - 1 ? WiC - 1 : wi);
        return base_plane[(b * HoC + 2 * hi) * WoC + 2 * wi];
    };

    auto mk = [&](int p, int bpgraw) -> TapSet {   // stage 2: ptrs + tap loads
        const int kh = PH(p) ? 2 : khA;
        const int kw = PW(p) ? 2 : kwA;
        int hi = (ho + 1 - kh) >> 1; hi = hi < 0 ? 0 : (hi > HiC - 1 ? HiC - 1 : hi);
        int wi = (wo + 1 - kw) >> 1; wi = wi < 0 ? 0 : (wi > WiC - 1 ? WiC - 1 : wi);
        const bool m = (PH(p) || mhA) && (PW(p) || mwA);   // B-positions always ok
        const float* ibase =
            images + (size_t)((b * HiC + hi) * WiC + wi) * (DiC * Cc);
        const int dE0 = hEc - (bpgraw >> 1);
        const int dE2 = dE0 - 1;
        const int dO1 = dE0 - q;
        const float4* pE0 = (const float4*)((m && dE0 >= 0 && dE0 < DiC)
                                                ? ibase + (size_t)dE0 * Cc : zpad);
        const float4* pE2 = (const float4*)((m && dE2 >= 0 && dE2 < DiC)
                                                ? ibase + (size_t)dE2 * Cc : zpad);
        const float4* pO1 = (const float4*)((m && dO1 >= 0 && dO1 < DiC)
                                                ? ibase + (size_t)dO1 * Cc : zpad);
        TapSet s; s.e0 = ldtap(pE0); s.e2 = ldtap(pE2); s.o1 = ldtap(pO1);
        return s;
    };

    auto kof = [&](int p) -> int {
        const int kh = PH(p) ? 2 : khA;
        const int kw = PW(p) ? 2 : kwA;
        return __builtin_amdgcn_readfirstlane((kh * 3 + kw) * (3 * Fc * Cc));
    };

    float accE[Fc] = {0, 0, 0, 0, 0, 0, 0, 0};
    float accO[Fc] = {0, 0, 0, 0, 0, 0, 0, 0};

    auto FMA = [&](const TapSet& s, int kidx) {
        const float* __restrict__ w = kern + kidx;   // uniform -> s_load
        #pragma unroll
        for (int f = 0; f < Fc; ++f) {
            accE[f] += dot16(s.e0, w + f * 16)              // kd=0
                     + dot16(s.e2, w + 2 * 128 + f * 16);   // kd=2
            accO[f] += dot16(s.o1, w + 1 * 128 + f * 16);   // kd=1
        }
    };

    // Software pipeline: bpg 2 deep, taps 1 deep.
    int bpg0 = bpload(0);
    int bpg1 = (npos > 1) ? bpload(1) : 0;
    TapSet X = mk(0, bpg0);
    int kc = kof(0);
    for (int p = 0; p + 1 < npos; ++p) {        // uniform trip count {0,1,3}
        const int bpgn = (p + 2 < npos) ? bpload(p + 2) : 0;
        TapSet Y = mk(p + 1, bpg1);             // issue loads BEFORE FMA(X)
        const int kn = kof(p + 1);
        FMA(X, kc);
        X = Y; kc = kn; bpg1 = bpgn;
    }
    FMA(X, kc);

    float* op = out + (size_t)((b * HoC + ho) * WoC + wo) * (DoC * Fc);
    float4* oE = (float4*)(op + doE * Fc);
    oE[0] = make_float4(accE[0], accE[1], accE[2], accE[3]);
    oE[1] = make_float4(accE[4], accE[5], accE[6], accE[7]);
    float4* oO = (float4*)(op + doO * Fc);
    oO[0] = make_float4(accO[0], accO[1], accO[2], accO[3]);
    oO[1] = make_float4(accO[4], accO[5], accO[6], accO[7]);
}

extern "C" void kernel_launch(void* const* d_in, const int* in_sizes, int n_in,
                              void* d_out, int out_size, void* d_ws, size_t ws_size,
                              hipStream_t stream) {
    const float* images     = (const float*)d_in[0];
    const int*   base_plane = (const int*)d_in[1];
    const float* kern       = (const float*)d_in[2];
    float* out = (float*)d_out;

    // 256 B zeros in workspace: branchless OOB-tap target (ws re-poisoned to
    // 0xAA before every timed launch, so memset on every call).
    hipMemsetAsync(d_ws, 0, 256, stream);

    dim3 grid(WoC / 8, HoC, Bc);   // 16 x 128 x 2 = 4096 blocks
    dim3 block(256);
    hipLaunchKernelGGL(sconv3dt_kernel, grid, block, 0, stream,
                       images, base_plane, kern, out, (const float*)d_ws);
}

// Round 7
// 107.643 us; speedup vs baseline: 1.5443x; 1.5443x over previous
//
#include <hip/hip_runtime.h>

// B=2, Hi=Wi=64, Di=32, C=16, F=8, strides (2,2,2), k=3x3x3, Ho=Wo=128, Do=64.
constexpr int Bc  = 2;
constexpr int HiC = 64, WiC = 64, DiC = 32;
constexpr int Cc  = 16, Fc  = 8;
constexpr int HoC = 128, WoC = 128, DoC = 64;

typedef __attribute__((ext_vector_type(8))) short short8;   // 8 bf16 = A/B frag
typedef __attribute__((ext_vector_type(4))) float f32x4;    // MFMA accumulator

// OOB-tap zero targets: __device__ constants, NOT workspace (round-5 lesson:
// never place anything in d_ws without checking ws_size — 8MB OOB => fault).
__device__ alignas(16) const float FZERO[8] = {0, 0, 0, 0, 0, 0, 0, 0};
__device__ alignas(16) const short HZERO[8] = {0, 0, 0, 0, 0, 0, 0, 0};

__device__ __forceinline__ unsigned pk2(float x, float y) {   // RNE f32x2 -> bf16x2
    unsigned ux = __float_as_uint(x), uy = __float_as_uint(y);
    ux += ((ux >> 16) & 1u) + 0x7FFFu;
    uy += ((uy >> 16) & 1u) + 0x7FFFu;
    return (ux >> 16) | (uy & 0xFFFF0000u);
}
__device__ __forceinline__ short8 pack8(float4 a, float4 b) {
    union { unsigned u[4]; short8 s; } r;
    r.u[0] = pk2(a.x, a.y); r.u[1] = pk2(a.z, a.w);
    r.u[2] = pk2(b.x, b.y); r.u[3] = pk2(b.z, b.w);
    return r.s;
}

// prepass (fast path only): images f32 -> bf16, same [b,hi,wi,di,c] layout
__global__ __launch_bounds__(256)
void imgcvt(const float4* __restrict__ in, uint2* __restrict__ outv, int n4) {
    int i = blockIdx.x * 256 + threadIdx.x;
    if (i < n4) {
        float4 v = in[i];
        uint2 o; o.x = pk2(v.x, v.y); o.y = pk2(v.z, v.w);
        outv[i] = o;
    }
}

// Per column: out[do,f] = sum over (pos,kd,c) packed into MFMA K=32 (2 taps x 16c).
// E rows (bp+do+1 even): per position one MFMA, k-halves = kd 0 / kd 2.
// O rows (kd=1): two positions packed per MFMA as the two k-halves.
// A frag: A[m=lane&15][k=quad*8+j]; B frag: B[k=quad*8+j][n=lane&15];
// C/D: col=lane&15, row=quad*4+reg (guide §3, m89-verified).
template<int CLS, int CVT>
__device__ __forceinline__ void doCols(const short* __restrict__ img16,
                                       const float* __restrict__ img32,
                                       const int*   __restrict__ bp,
                                       const float* __restrict__ kern,
                                       float*       __restrict__ out,
                                       float*       __restrict__ ldsw,
                                       int b, int ho, int wo0, int lane) {
    constexpr int NP = (CLS == 0) ? 1 : ((CLS == 3) ? 4 : 2);
    constexpr int OP = (NP + 1) / 2;
    constexpr int KH[4][4] = {{1,0,0,0},{1,1,0,0},{0,2,0,0},{0,0,2,2}};
    constexpr int KW[4][4] = {{1,0,0,0},{0,2,0,0},{1,1,0,0},{0,2,0,2}};

    const int quad = lane >> 4, n = lane & 15;
    const int half = quad >> 1, chalf = quad & 1;   // k-half, channel-half

    // ---- B fragments built in-register from f32 kern (no ws dependency) ----
    short8 bE[NP], bO[OP];
    #pragma unroll
    for (int p = 0; p < NP; ++p) {
        const int kp = KH[CLS][p] * 3 + KW[CLS][p];
        const float* wp = (n < Fc)
            ? kern + (kp * 3 + 2 * half) * 128 + n * 16 + chalf * 8 : FZERO;
        bE[p] = pack8(*(const float4*)wp, *(const float4*)(wp + 4));
    }
    #pragma unroll
    for (int pp = 0; pp < OP; ++pp) {
        const int  PA   = (2 * pp < NP) ? 2 * pp : 0;        // const after unroll
        const bool hasB = (2 * pp + 1) < NP;
        const int  PB   = hasB ? (2 * pp + 1) : 0;
        const int kpa = KH[CLS][PA] * 3 + KW[CLS][PA];
        const int kpb = KH[CLS][PB] * 3 + KW[CLS][PB];
        const int kp  = half ? kpb : kpa;
        const bool v  = (n < Fc) && (!half || hasB);
        const float* wp = v ? kern + (kp * 3 + 1) * 128 + n * 16 + chalf * 8 : FZERO;
        bO[pp] = pack8(*(const float4*)wp, *(const float4*)(wp + 4));
    }

    #pragma unroll
    for (int cc = 0; cc < 2; ++cc) {
        const int wo     = wo0 + 2 * cc;
        const int colidx = (b * HoC + ho) * WoC + wo;
        const int bp_col = bp[colidx];
        const int q      = (bp_col + 1) & 1;
        const int baseE  = (bp_col + q + 1) >> 1;   // di(kd0) = baseE+m-bpg
        const int baseO  = (bp_col + 1 - q) >> 1;   // di(kd1) = baseO+m-bpg

        int bpg[4]; size_t pixo[4]; bool pv[4];
        #pragma unroll
        for (int p = 0; p < NP; ++p) {
            const int kh = KH[CLS][p], kw = KW[CLS][p];
            int hi = (ho + 1 - kh) >> 1; hi = hi > HiC - 1 ? HiC - 1 : hi;
            int wi = (wo + 1 - kw) >> 1; wi = wi > WiC - 1 ? WiC - 1 : wi;
            pv[p]   = (kh != 0 || ho + 1 < HoC) && (kw != 0 || wo + 1 < WoC);
            bpg[p]  = bp[(b * HoC + 2 * hi) * WoC + 2 * wi] >> 1;
            pixo[p] = (size_t)((b * HiC + hi) * WiC + wi) * (DiC * Cc);
        }

        f32x4 accE[2] = {{0.f,0.f,0.f,0.f},{0.f,0.f,0.f,0.f}};
        f32x4 accO[2] = {{0.f,0.f,0.f,0.f},{0.f,0.f,0.f,0.f}};

        #pragma unroll
        for (int g = 0; g < 2; ++g) {
            const int m = 16 * g + n;   // depth-pair index (A row + row-group)
            #pragma unroll
            for (int p = 0; p < NP; ++p) {          // E: kd = 2*half
                const int  di = baseE + m - bpg[p] - half;
                const bool ok = pv[p] && di >= 0 && di < DiC;
                short8 a;
                if constexpr (CVT) {
                    const float* ap = ok ? img32 + pixo[p] + di * Cc + chalf * 8 : FZERO;
                    a = pack8(*(const float4*)ap, *(const float4*)(ap + 4));
                } else {
                    const short* ap = ok ? img16 + pixo[p] + di * Cc + chalf * 8 : HZERO;
                    a = *(const short8*)ap;
                }
                accE[g] = __builtin_amdgcn_mfma_f32_16x16x32_bf16(a, bE[p], accE[g], 0, 0, 0);
            }
            #pragma unroll
            for (int pp = 0; pp < OP; ++pp) {       // O: k-halves = two positions
                const int  PA   = (2 * pp < NP) ? 2 * pp : 0;
                const bool hasB = (2 * pp + 1) < NP;
                const int  PB   = hasB ? (2 * pp + 1) : 0;
                const int    bpgs = half ? bpg[PB] : bpg[PA];
                const size_t po   = half ? pixo[PB] : pixo[PA];
                const bool   pvs  = half ? (hasB && pv[PB]) : pv[PA];
                const int  di = baseO + m - bpgs;
                const bool ok = pvs && di >= 0 && di < DiC;
                short8 a;
                if constexpr (CVT) {
                    const float* ap = ok ? img32 + po + di * Cc + chalf * 8 : FZERO;
                    a = pack8(*(const float4*)ap, *(const float4*)(ap + 4));
                } else {
                    const short* ap = ok ? img16 + po + di * Cc + chalf * 8 : HZERO;
                    a = *(const short8*)ap;
                }
                accO[g] = __builtin_amdgcn_mfma_f32_16x16x32_bf16(a, bO[pp], accO[g], 0, 0, 0);
            }
        }

        // Wave-private LDS transpose: C/D (row=quad*4+r, col=n) -> [do][f] rows.
        __builtin_amdgcn_wave_barrier();
        if (n < Fc) {
            #pragma unroll
            for (int g = 0; g < 2; ++g) {
                #pragma unroll
                for (int r = 0; r < 4; ++r) {
                    const int m2 = 16 * g + quad * 4 + r;
                    ldsw[(2 * m2 + q) * Fc + n]     = accE[g][r];
                    ldsw[(2 * m2 + 1 - q) * Fc + n] = accO[g][r];
                }
            }
        }
        __builtin_amdgcn_wave_barrier();
        float* outc = out + (size_t)colidx * (DoC * Fc);
        *(float4*)(outc + lane * 8)     = *(const float4*)(ldsw + lane * 8);
        *(float4*)(outc + lane * 8 + 4) = *(const float4*)(ldsw + lane * 8 + 4);
        __builtin_amdgcn_wave_barrier();
    }
}

template<int CVT>
__global__ __launch_bounds__(256, 3)
void sconv_mfma(const short* __restrict__ img16, const float* __restrict__ img32,
                const int* __restrict__ bp, const float* __restrict__ kern,
                float* __restrict__ out) {
    __shared__ float lds[4 * DoC * Fc];   // 8 KiB, one 2 KiB slice per wave
    const int t = threadIdx.x, wv = t >> 6, lane = t & 63;
    const int b = blockIdx.z, ho = blockIdx.y;
    const int wo0 = (blockIdx.x << 3) + (wv & 1) + ((wv >> 1) << 2);
    float* ldsw = lds + wv * (DoC * Fc);
    if (ho & 1) {
        if (wv & 1) doCols<3, CVT>(img16, img32, bp, kern, out, ldsw, b, ho, wo0, lane);
        else        doCols<2, CVT>(img16, img32, bp, kern, out, ldsw, b, ho, wo0, lane);
    } else {
        if (wv & 1) doCols<1, CVT>(img16, img32, bp, kern, out, ldsw, b, ho, wo0, lane);
        else        doCols<0, CVT>(img16, img32, bp, kern, out, ldsw, b, ho, wo0, lane);
    }
}

extern "C" void kernel_launch(void* const* d_in, const int* in_sizes, int n_in,
                              void* d_out, int out_size, void* d_ws, size_t ws_size,
                              hipStream_t stream) {
    const float* images = (const float*)d_in[0];
    const int*   bp     = (const int*)d_in[1];
    const float* kern   = (const float*)d_in[2];
    float* out = (float*)d_out;

    const size_t imgElems = (size_t)Bc * HiC * WiC * DiC * Cc;   // 4,194,304
    const size_t needWs   = imgElems * sizeof(short);            // 8 MiB

    dim3 grid(WoC / 8, HoC, Bc), block(256);
    if (ws_size >= needWs) {
        // fast path: pre-convert images to bf16 in ws (size-checked)
        const int n4 = (int)(imgElems / 4);                      // 1,048,576
        hipLaunchKernelGGL(imgcvt, dim3(n4 / 256), dim3(256), 0, stream,
                           (const float4*)images, (uint2*)d_ws, n4);
        hipLaunchKernelGGL((sconv_mfma<0>), grid, block, 0, stream,
                           (const short*)d_ws, images, bp, kern, out);
    } else {
        // fallback: convert f32 -> bf16 inline in the main kernel; ws untouched
        hipLaunchKernelGGL((sconv_mfma<1>), grid, block, 0, stream,
                           (const short*)nullptr, images, bp, kern, out);
    }
}

// Round 8
// 103.737 us; speedup vs baseline: 1.6024x; 1.0377x over previous
//
#include <hip/hip_runtime.h>

// B=2, Hi=Wi=64, Di=32, C=16, F=8, strides (2,2,2), k=3x3x3, Ho=Wo=128, Do=64.
constexpr int Bc  = 2;
constexpr int HiC = 64, WiC = 64, DiC = 32;
constexpr int Cc  = 16, Fc  = 8;
constexpr int HoC = 128, WoC = 128, DoC = 64;
constexpr int IMG_ELEMS = Bc * HiC * WiC * DiC * Cc;   // 4,194,304 bf16 elems

typedef __attribute__((ext_vector_type(8))) short short8;   // 8 bf16 = A/B frag
typedef __attribute__((ext_vector_type(4))) float f32x4;    // MFMA accumulator

__device__ alignas(16) const float FZERO[8] = {0, 0, 0, 0, 0, 0, 0, 0};

__device__ __forceinline__ unsigned pk2(float x, float y) {   // RNE f32x2 -> bf16x2
    unsigned ux = __float_as_uint(x), uy = __float_as_uint(y);
    ux += ((ux >> 16) & 1u) + 0x7FFFu;
    uy += ((uy >> 16) & 1u) + 0x7FFFu;
    return (ux >> 16) | (uy & 0xFFFF0000u);
}
__device__ __forceinline__ short8 pack8(float4 a, float4 b) {
    union { unsigned u[4]; short8 s; } r;
    r.u[0] = pk2(a.x, a.y); r.u[1] = pk2(a.z, a.w);
    r.u[2] = pk2(b.x, b.y); r.u[3] = pk2(b.z, b.w);
    return r.s;
}

// prepass: images f32 -> bf16 into ws, plus a 64 B zero row at the tail
// (OOB taps load from it with a single 32-bit offset cndmask — no 64b ptr select).
__global__ __launch_bounds__(256)
void imgcvt(const float4* __restrict__ in, uint2* __restrict__ outv, int n4) {
    int i = blockIdx.x * 256 + threadIdx.x;
    if (i < n4) {
        float4 v = in[i];
        uint2 o; o.x = pk2(v.x, v.y); o.y = pk2(v.z, v.w);
        outv[i] = o;
    } else if (i < n4 + 8) {
        uint2 z; z.x = 0u; z.y = 0u;
        outv[i] = z;                       // zero row: elems [IMG_ELEMS, +32)
    }
}

// Per column: out[do,f] = sum over (pos,kd,c) packed into MFMA K=32 (2 taps x 16c).
// E rows (bp+do+1 even): per position one MFMA, k-halves = kd 0 / kd 2.
// O rows (kd=1): two positions packed per MFMA as the two k-halves.
// A frag: A[m=lane&15][k=quad*8+j]; B frag: B[k=quad*8+j][n=lane&15];
// C/D: col=lane&15, row=quad*4+reg. (round-7 verified end-to-end)
// All wave-uniform values forced scalar via readfirstlane.
template<int CLS, int CVT>
__device__ __forceinline__ void doCols(const short* __restrict__ img16,
                                       const float* __restrict__ img32,
                                       const int*   __restrict__ bp,
                                       const float* __restrict__ kern,
                                       float*       __restrict__ out,
                                       float*       __restrict__ ldsw,
                                       int b, int ho, int wo0, int lane) {
    constexpr int NP = (CLS == 0) ? 1 : ((CLS == 3) ? 4 : 2);
    constexpr int OP = (NP + 1) / 2;
    constexpr int KH[4][4] = {{1,0,0,0},{1,1,0,0},{0,2,0,0},{0,0,2,2}};
    constexpr int KW[4][4] = {{1,0,0,0},{0,2,0,0},{1,1,0,0},{0,2,0,2}};

    const int quad = lane >> 4, n = lane & 15;
    const int half = quad >> 1, chalf = quad & 1;   // k-half, channel-half

    // ---- B fragments in-register from f32 kern ----
    short8 bE[NP], bO[OP];
    #pragma unroll
    for (int p = 0; p < NP; ++p) {
        const int kp = KH[CLS][p] * 3 + KW[CLS][p];
        const float* wp = (n < Fc)
            ? kern + (kp * 3 + 2 * half) * 128 + n * 16 + chalf * 8 : FZERO;
        bE[p] = pack8(*(const float4*)wp, *(const float4*)(wp + 4));
    }
    #pragma unroll
    for (int pp = 0; pp < OP; ++pp) {
        const int  PA   = (2 * pp < NP) ? 2 * pp : 0;
        const bool hasB = (2 * pp + 1) < NP;
        const int  PB   = hasB ? (2 * pp + 1) : 0;
        const int kpa = KH[CLS][PA] * 3 + KW[CLS][PA];
        const int kpb = KH[CLS][PB] * 3 + KW[CLS][PB];
        const int kp  = half ? kpb : kpa;
        const bool v  = (n < Fc) && (!half || hasB);
        const float* wp = v ? kern + (kp * 3 + 1) * 128 + n * 16 + chalf * 8 : FZERO;
        bO[pp] = pack8(*(const float4*)wp, *(const float4*)(wp + 4));
    }

    #pragma unroll
    for (int cc = 0; cc < 2; ++cc) {
        const int wo     = wo0 + 2 * cc;
        const int colidx = __builtin_amdgcn_readfirstlane((b * HoC + ho) * WoC + wo);
        const int bp_col = bp[colidx];              // uniform idx -> s_load
        const int q      = (bp_col + 1) & 1;
        const int baseE  = (bp_col + q + 1) >> 1;   // di(kd0) = baseE+m-bpg
        const int baseO  = (bp_col + 1 - q) >> 1;   // di(kd1) = baseO+m-bpg

        int sE[4], sO[4], pxo[4]; bool pv[4];
        #pragma unroll
        for (int p = 0; p < NP; ++p) {
            const int kh = KH[CLS][p], kw = KW[CLS][p];
            int hi = (ho + 1 - kh) >> 1; hi = hi > HiC - 1 ? HiC - 1 : hi;
            int wi = (wo + 1 - kw) >> 1; wi = wi > WiC - 1 ? WiC - 1 : wi;
            pv[p] = (kh != 0 || ho + 1 < HoC) && (kw != 0 || wo + 1 < WoC);
            const int sidx =
                __builtin_amdgcn_readfirstlane((b * HoC + 2 * hi) * WoC + 2 * wi);
            const int bpg = bp[sidx] >> 1;          // s_load, scalar math
            sE[p]  = baseE - bpg;                   // di_E = sE[p] + m - half
            sO[p]  = baseO - bpg;                   // di_O = sO[p] + m
            pxo[p] = __builtin_amdgcn_readfirstlane(
                         ((b * HiC + hi) * WiC + wi) * (DiC * Cc));
        }

        f32x4 accE[2] = {{0.f,0.f,0.f,0.f},{0.f,0.f,0.f,0.f}};
        f32x4 accO[2] = {{0.f,0.f,0.f,0.f},{0.f,0.f,0.f,0.f}};

        #pragma unroll
        for (int g = 0; g < 2; ++g) {
            const int m = 16 * g + n;   // depth-pair index (A row + row-group)
            #pragma unroll
            for (int p = 0; p < NP; ++p) {          // E: kd = 2*half
                const int  di = sE[p] + m - half;
                const bool ok = pv[p] && ((unsigned)di < (unsigned)DiC);
                short8 a;
                if constexpr (CVT) {
                    const float* ap = ok ? img32 + pxo[p] + di * Cc + chalf * 8 : FZERO;
                    a = pack8(*(const float4*)ap, *(const float4*)(ap + 4));
                } else {
                    const int off = ok ? pxo[p] + di * Cc + chalf * 8 : IMG_ELEMS;
                    a = *(const short8*)(img16 + off);
                }
                accE[g] = __builtin_amdgcn_mfma_f32_16x16x32_bf16(a, bE[p], accE[g], 0, 0, 0);
            }
            #pragma unroll
            for (int pp = 0; pp < OP; ++pp) {       // O: k-halves = two positions
                const int  PA   = (2 * pp < NP) ? 2 * pp : 0;
                const bool hasB = (2 * pp + 1) < NP;
                const int  PB   = hasB ? (2 * pp + 1) : 0;
                const int  sOs  = half ? sO[PB] : sO[PA];
                const int  pxs  = half ? pxo[PB] : pxo[PA];
                const bool pvs  = half ? (hasB && pv[PB]) : pv[PA];
                const int  di = sOs + m;
                const bool ok = pvs && ((unsigned)di < (unsigned)DiC);
                short8 a;
                if constexpr (CVT) {
                    const float* ap = ok ? img32 + pxs + di * Cc + chalf * 8 : FZERO;
                    a = pack8(*(const float4*)ap, *(const float4*)(ap + 4));
                } else {
                    const int off = ok ? pxs + di * Cc + chalf * 8 : IMG_ELEMS;
                    a = *(const short8*)(img16 + off);
                }
                accO[g] = __builtin_amdgcn_mfma_f32_16x16x32_bf16(a, bO[pp], accO[g], 0, 0, 0);
            }
        }

        // Wave-private LDS transpose: C/D (row=quad*4+r, col=n) -> [do][f] rows.
        __builtin_amdgcn_wave_barrier();
        if (n < Fc) {
            #pragma unroll
            for (int g = 0; g < 2; ++g) {
                #pragma unroll
                for (int r = 0; r < 4; ++r) {
                    const int m2 = 16 * g + quad * 4 + r;
                    ldsw[(2 * m2 + q) * Fc + n]     = accE[g][r];
                    ldsw[(2 * m2 + 1 - q) * Fc + n] = accO[g][r];
                }
            }
        }
        __builtin_amdgcn_wave_barrier();
        float* outc = out + (size_t)colidx * (DoC * Fc);
        *(float4*)(outc + lane * 8)     = *(const float4*)(ldsw + lane * 8);
        *(float4*)(outc + lane * 8 + 4) = *(const float4*)(ldsw + lane * 8 + 4);
        __builtin_amdgcn_wave_barrier();
    }
}

template<int CVT>
__global__ __launch_bounds__(256, 3)
void sconv_mfma(const short* __restrict__ img16, const float* __restrict__ img32,
                const int* __restrict__ bp, const float* __restrict__ kern,
                float* __restrict__ out) {
    __shared__ float lds[4 * DoC * Fc];   // 8 KiB, one 2 KiB slice per wave
    const int t = threadIdx.x, wv = t >> 6, lane = t & 63;
    const int b = blockIdx.z, ho = blockIdx.y;
    const int wo0 = (blockIdx.x << 3) + (wv & 1) + ((wv >> 1) << 2);
    float* ldsw = lds + wv * (DoC * Fc);
    if (ho & 1) {
        if (wv & 1) doCols<3, CVT>(img16, img32, bp, kern, out, ldsw, b, ho, wo0, lane);
        else        doCols<2, CVT>(img16, img32, bp, kern, out, ldsw, b, ho, wo0, lane);
    } else {
        if (wv & 1) doCols<1, CVT>(img16, img32, bp, kern, out, ldsw, b, ho, wo0, lane);
        else        doCols<0, CVT>(img16, img32, bp, kern, out, ldsw, b, ho, wo0, lane);
    }
}

extern "C" void kernel_launch(void* const* d_in, const int* in_sizes, int n_in,
                              void* d_out, int out_size, void* d_ws, size_t ws_size,
                              hipStream_t stream) {
    const float* images = (const float*)d_in[0];
    const int*   bp     = (const int*)d_in[1];
    const float* kern   = (const float*)d_in[2];
    float* out = (float*)d_out;

    const size_t needWs = ((size_t)IMG_ELEMS + 32) * sizeof(short);  // 8 MiB + 64 B

    dim3 grid(WoC / 8, HoC, Bc), block(256);
    if (ws_size >= needWs) {
        // fast path: bf16 image + tail zero row in ws (size-checked; round-5 lesson)
        const int n4 = IMG_ELEMS / 4;                                // 1,048,576
        hipLaunchKernelGGL(imgcvt, dim3(n4 / 256 + 1), dim3(256), 0, stream,
                           (const float4*)images, (uint2*)d_ws, n4);
        hipLaunchKernelGGL((sconv_mfma<0>), grid, block, 0, stream,
                           (const short*)d_ws, images, bp, kern, out);
    } else {
        // fallback: inline f32->bf16 conversion; ws untouched
        hipLaunchKernelGGL((sconv_mfma<1>), grid, block, 0, stream,
                           (const short*)nullptr, images, bp, kern, out);
    }
}

// Round 9
// 99.949 us; speedup vs baseline: 1.6632x; 1.0379x over previous
//
#include <hip/hip_runtime.h>

// B=2, Hi=Wi=64, Di=32, C=16, F=8, strides (2,2,2), k=3x3x3, Ho=Wo=128, Do=64.
constexpr int Bc  = 2;
constexpr int HiC = 64, WiC = 64, DiC = 32;
constexpr int Cc  = 16, Fc  = 8;
constexpr int HoC = 128, WoC = 128, DoC = 64;
constexpr int IMG_ELEMS = Bc * HiC * WiC * DiC * Cc;   // 4,194,304 bf16 elems

typedef __attribute__((ext_vector_type(8))) short short8;   // 8 bf16 = A/B frag
typedef __attribute__((ext_vector_type(4))) float f32x4;    // MFMA accumulator

__device__ alignas(16) const float FZERO[8] = {0, 0, 0, 0, 0, 0, 0, 0};

__device__ __forceinline__ unsigned pk2(float x, float y) {   // RNE f32x2 -> bf16x2
    unsigned ux = __float_as_uint(x), uy = __float_as_uint(y);
    ux += ((ux >> 16) & 1u) + 0x7FFFu;
    uy += ((uy >> 16) & 1u) + 0x7FFFu;
    return (ux >> 16) | (uy & 0xFFFF0000u);
}
__device__ __forceinline__ short8 pack8(float4 a, float4 b) {
    union { unsigned u[4]; short8 s; } r;
    r.u[0] = pk2(a.x, a.y); r.u[1] = pk2(a.z, a.w);
    r.u[2] = pk2(b.x, b.y); r.u[3] = pk2(b.z, b.w);
    return r.s;
}

// prepass: images f32 -> bf16 into ws + 64 B zero row at tail (OOB-tap target,
// selected with one 32-bit offset cndmask).
__global__ __launch_bounds__(256)
void imgcvt(const float4* __restrict__ in, uint2* __restrict__ outv, int n4) {
    int i = blockIdx.x * 256 + threadIdx.x;
    if (i < n4) {
        float4 v = in[i];
        uint2 o; o.x = pk2(v.x, v.y); o.y = pk2(v.z, v.w);
        outv[i] = o;
    } else if (i < n4 + 8) {
        uint2 z; z.x = 0u; z.y = 0u;
        outv[i] = z;                       // zero row: elems [IMG_ELEMS, +32)
    }
}

// Wave = 4 same-parity columns. Per column: out[do,f] over (pos,kd,c) packed in
// MFMA K=32. E rows (bp+do+1 even): per position, k-halves = kd0/kd2. O rows
// (kd=1): two positions per MFMA. A: A[m=lane&15][k=quad*8+j]; B: B[k][n=lane&15];
// C/D: col=lane&15, row=quad*4+reg. (round-7/8 verified end-to-end)
// Phase 1 issues ALL scalar loads (bp_col + bpg, geometric addrs) up front;
// validity is folded into a scalar sentinel so per-tap test is one unsigned cmp.
template<int CLS, int CVT>
__device__ __forceinline__ void doCols(const short* __restrict__ img16,
                                       const float* __restrict__ img32,
                                       const int*   __restrict__ bp,
                                       const float* __restrict__ kern,
                                       float*       __restrict__ out,
                                       float*       __restrict__ ldsw,
                                       int b, int ho, int wo0, int lane) {
    constexpr int NP = (CLS == 0) ? 1 : ((CLS == 3) ? 4 : 2);
    constexpr int OP = (NP + 1) / 2;
    constexpr int KH[4][4] = {{1,0,0,0},{1,1,0,0},{0,2,0,0},{0,0,2,2}};
    constexpr int KW[4][4] = {{1,0,0,0},{0,2,0,0},{1,1,0,0},{0,2,0,2}};

    const int quad = lane >> 4, n = lane & 15;
    const int half = quad >> 1, chalf = quad & 1;   // k-half, channel-half

    // ---- B fragments in-register from f32 kern (amortized over 4 columns) ----
    short8 bE[NP], bO[OP];
    #pragma unroll
    for (int p = 0; p < NP; ++p) {
        const int kp = KH[CLS][p] * 3 + KW[CLS][p];
        const float* wp = (n < Fc)
            ? kern + (kp * 3 + 2 * half) * 128 + n * 16 + chalf * 8 : FZERO;
        bE[p] = pack8(*(const float4*)wp, *(const float4*)(wp + 4));
    }
    #pragma unroll
    for (int pp = 0; pp < OP; ++pp) {
        const int  PA   = (2 * pp < NP) ? 2 * pp : 0;
        const bool hasB = (2 * pp + 1) < NP;
        const int  PB   = hasB ? (2 * pp + 1) : 0;
        const int kpa = KH[CLS][PA] * 3 + KW[CLS][PA];
        const int kpb = KH[CLS][PB] * 3 + KW[CLS][PB];
        const int kp  = half ? kpb : kpa;
        const bool v  = (n < Fc) && (!half || hasB);
        const float* wp = v ? kern + (kp * 3 + 1) * 128 + n * 16 + chalf * 8 : FZERO;
        bO[pp] = pack8(*(const float4*)wp, *(const float4*)(wp + 4));
    }

    // ---- phase 1: ALL scalar loads for all 4 columns ----
    int colx[4], bpcol[4], bpgr[4][NP], pxo[4][NP]; bool pvs[4][NP];
    #pragma unroll
    for (int cc = 0; cc < 4; ++cc) {
        const int wo = wo0 + 2 * cc;
        colx[cc]  = __builtin_amdgcn_readfirstlane((b * HoC + ho) * WoC + wo);
        bpcol[cc] = bp[colx[cc]];                    // uniform -> s_load
        #pragma unroll
        for (int p = 0; p < NP; ++p) {
            const int kh = KH[CLS][p], kw = KW[CLS][p];
            int hi = (ho + 1 - kh) >> 1; hi = hi > HiC - 1 ? HiC - 1 : hi;
            int wi = (wo + 1 - kw) >> 1; wi = wi > WiC - 1 ? WiC - 1 : wi;
            pvs[cc][p] = (kh != 0 || ho + 1 < HoC) && (kw != 0 || wo + 1 < WoC);
            const int sidx =
                __builtin_amdgcn_readfirstlane((b * HoC + 2 * hi) * WoC + 2 * wi);
            bpgr[cc][p] = bp[sidx];                  // uniform -> s_load
            pxo[cc][p]  = __builtin_amdgcn_readfirstlane(
                              ((b * HiC + hi) * WiC + wi) * (DiC * Cc));
        }
    }

    // ---- phase 2: per column taps + MFMA + epilogue ----
    #pragma unroll
    for (int cc = 0; cc < 4; ++cc) {
        const int bp_col = bpcol[cc];
        const int q      = (bp_col + 1) & 1;
        const int baseE  = (bp_col + q + 1) >> 1;    // di(kd0) = baseE+m-bpg
        const int baseO  = (bp_col + 1 - q) >> 1;    // di(kd1) = baseO+m-bpg
        int sE[NP], sO[NP];
        #pragma unroll
        for (int p = 0; p < NP; ++p) {               // sentinel folds validity
            const int bpg = bpgr[cc][p] >> 1;
            sE[p] = pvs[cc][p] ? baseE - bpg : -100000;
            sO[p] = pvs[cc][p] ? baseO - bpg : -100000;
        }

        f32x4 accE[2] = {{0.f,0.f,0.f,0.f},{0.f,0.f,0.f,0.f}};
        f32x4 accO[2] = {{0.f,0.f,0.f,0.f},{0.f,0.f,0.f,0.f}};

        #pragma unroll
        for (int g = 0; g < 2; ++g) {
            #pragma unroll
            for (int p = 0; p < NP; ++p) {           // E: kd = 2*half
                const int  di = sE[p] + 16 * g + n - half;
                const bool ok = (unsigned)di < (unsigned)DiC;
                short8 a;
                if constexpr (CVT) {
                    const float* ap = ok ? img32 + pxo[cc][p] + di * Cc + chalf * 8 : FZERO;
                    a = pack8(*(const float4*)ap, *(const float4*)(ap + 4));
                } else {
                    const int off = ok ? pxo[cc][p] + di * Cc + chalf * 8 : IMG_ELEMS;
                    a = *(const short8*)(img16 + off);
                }
                accE[g] = __builtin_amdgcn_mfma_f32_16x16x32_bf16(a, bE[p], accE[g], 0, 0, 0);
            }
            #pragma unroll
            for (int pp = 0; pp < OP; ++pp) {        // O: k-halves = two positions
                const int  PA   = (2 * pp < NP) ? 2 * pp : 0;
                const bool hasB = (2 * pp + 1) < NP;
                const int  PB   = hasB ? (2 * pp + 1) : 0;
                const int  sOs  = half ? (hasB ? sO[PB] : -100000) : sO[PA];
                const int  pxs  = half ? pxo[cc][PB] : pxo[cc][PA];
                const int  di = sOs + 16 * g + n;
                const bool ok = (unsigned)di < (unsigned)DiC;
                short8 a;
                if constexpr (CVT) {
                    const float* ap = ok ? img32 + pxs + di * Cc + chalf * 8 : FZERO;
                    a = pack8(*(const float4*)ap, *(const float4*)(ap + 4));
                } else {
                    const int off = ok ? pxs + di * Cc + chalf * 8 : IMG_ELEMS;
                    a = *(const short8*)(img16 + off);
                }
                accO[g] = __builtin_amdgcn_mfma_f32_16x16x32_bf16(a, bO[pp], accO[g], 0, 0, 0);
            }
        }

        // Wave-private LDS transpose: C/D (row=quad*4+r, col=n) -> [do][f] rows.
        __builtin_amdgcn_wave_barrier();
        if (n < Fc) {
            #pragma unroll
            for (int g = 0; g < 2; ++g) {
                #pragma unroll
                for (int r = 0; r < 4; ++r) {
                    const int m2 = 16 * g + quad * 4 + r;
                    ldsw[(2 * m2 + q) * Fc + n]     = accE[g][r];
                    ldsw[(2 * m2 + 1 - q) * Fc + n] = accO[g][r];
                }
            }
        }
        __builtin_amdgcn_wave_barrier();
        float* outc = out + (size_t)colx[cc] * (DoC * Fc);
        *(float4*)(outc + lane * 8)     = *(const float4*)(ldsw + lane * 8);
        *(float4*)(outc + lane * 8 + 4) = *(const float4*)(ldsw + lane * 8 + 4);
        __builtin_amdgcn_wave_barrier();
    }
}

template<int CVT>
__global__ __launch_bounds__(256, 3)
void sconv_mfma(const short* __restrict__ img16, const float* __restrict__ img32,
                const int* __restrict__ bp, const float* __restrict__ kern,
                float* __restrict__ out) {
    __shared__ float lds[4 * DoC * Fc];   // 8 KiB, one 2 KiB slice per wave
    const int t = threadIdx.x, wv = t >> 6, lane = t & 63;
    const int b = blockIdx.z, ho = blockIdx.y;
    // block covers 16 wo; wave wv covers 4 same-parity columns wo0 + {0,2,4,6}
    const int wo0 = (blockIdx.x << 4) + (wv & 1) + ((wv >> 1) << 3);
    float* ldsw = lds + wv * (DoC * Fc);
    if (ho & 1) {
        if (wv & 1) doCols<3, CVT>(img16, img32, bp, kern, out, ldsw, b, ho, wo0, lane);
        else        doCols<2, CVT>(img16, img32, bp, kern, out, ldsw, b, ho, wo0, lane);
    } else {
        if (wv & 1) doCols<1, CVT>(img16, img32, bp, kern, out, ldsw, b, ho, wo0, lane);
        else        doCols<0, CVT>(img16, img32, bp, kern, out, ldsw, b, ho, wo0, lane);
    }
}

extern "C" void kernel_launch(void* const* d_in, const int* in_sizes, int n_in,
                              void* d_out, int out_size, void* d_ws, size_t ws_size,
                              hipStream_t stream) {
    const float* images = (const float*)d_in[0];
    const int*   bp     = (const int*)d_in[1];
    const float* kern   = (const float*)d_in[2];
    float* out = (float*)d_out;

    const size_t needWs = ((size_t)IMG_ELEMS + 32) * sizeof(short);  // 8 MiB + 64 B

    dim3 grid(WoC / 16, HoC, Bc), block(256);   // 8 x 128 x 2 = 2048 blocks
    if (ws_size >= needWs) {
        // fast path: bf16 image + tail zero row in ws (size-checked; round-5 lesson)
        const int n4 = IMG_ELEMS / 4;                                // 1,048,576
        hipLaunchKernelGGL(imgcvt, dim3(n4 / 256 + 1), dim3(256), 0, stream,
                           (const float4*)images, (uint2*)d_ws, n4);
        hipLaunchKernelGGL((sconv_mfma<0>), grid, block, 0, stream,
                           (const short*)d_ws, images, bp, kern, out);
    } else {
        // fallback: inline f32->bf16 conversion; ws untouched
        hipLaunchKernelGGL((sconv_mfma<1>), grid, block, 0, stream,
                           (const short*)nullptr, images, bp, kern, out);
    }
}